// Round 11
// baseline (546.864 us; speedup 1.0000x reference)
//
#include <hip/hip_runtime.h>
#include <hip/hip_bf16.h>

#define B_   512
#define N_   128
#define H_   256
#define NH_  8
#define HD_  32
#define DEG_ 8
#define R_   (B_ * N_)          // 65536 rows
#define E_   (B_ * N_ * DEG_)   // 524288 edges
#define EPG_ (N_ * DEG_)        // 1024 edges per graph

typedef unsigned short u16;
typedef unsigned int u32;

typedef __attribute__((ext_vector_type(8))) short s16x8;   // 8 bf16 = 4 VGPRs
typedef __attribute__((ext_vector_type(4))) float f32x4;   // MFMA acc

__device__ __forceinline__ float b2f(u16 u) {
  union { u32 i; float f; } v;
  v.i = ((u32)u) << 16;
  return v.f;
}
__device__ __forceinline__ u16 f2b(float f) {
  union { float f; u32 u; } v;
  v.f = f;
  u32 r = (v.u + 0x7fffu + ((v.u >> 16) & 1u)) >> 16;  // RNE
  return (u16)r;
}
__device__ __forceinline__ void ld4b(const u16* p, float* o) {
  ushort4 v = *(const ushort4*)p;
  o[0] = b2f(v.x); o[1] = b2f(v.y); o[2] = b2f(v.z); o[3] = b2f(v.w);
}

// ---------------------------------------------------------------------------
// Tiled-swizzled layout for ALL 256-col bf16 intermediates:
//   [rowblk=row>>7][kstep=col>>6][row&127][seg: ((col>>3)&7)^(row&7)][col&7]
// A 64-row x 64-col panel is one contiguous 8 KB run -> GEMM A-staging is a
// pure linear burst; the LDS XOR swizzle is pre-baked at every producer.
// ---------------------------------------------------------------------------
__device__ __forceinline__ int tix(int row, int col) {
  return ((row >> 7) << 15) + (((col >> 6) & 3) << 13) + ((row & 127) << 6) +
         (((((col >> 3) & 7) ^ (row & 7))) << 3) + (col & 7);
}

__device__ __forceinline__ void glds16(const u16* g, u16* l) {
  __builtin_amdgcn_global_load_lds(
      (const __attribute__((address_space(1))) void*)g,
      (__attribute__((address_space(3))) void*)l, 16, 0, 0);
}

// stats layout (floats, at d_ws + 0):
//   0..255 sum_local | 256..511 sq_local | 512..767 sum_attn | 768..1023 sq_attn
//   1024..1279 sum_out | 1280..1535 sq_out
//   1536 a_local | 1792 b_local | 2048 a_attn | 2304 b_attn | 2560 a_out | 2816 b_out

// packed bf16 weight area offsets (u16 elements)
#define OFF_GW1 0
#define OFF_GB1 65536
#define OFF_GW2 65792
#define OFF_GB2 131328
#define OFF_AIW 131584
#define OFF_AIB 328192
#define OFF_AOW 328960
#define OFF_AOB 394496
#define OFF_F1W 394752
#define OFF_F1B 525824
#define OFF_F2W 526336
#define OFF_F2B 657408
#define W_TOTAL 657664

__global__ void zero_stats(float* __restrict__ st) {
  st[blockIdx.x * 256 + threadIdx.x] = 0.f;
}

// fp32 (linear) -> bf16 (tiled) for h
__global__ __launch_bounds__(256) void cvt_h(const float* __restrict__ src,
                                             u16* __restrict__ dst) {
  const int e = (blockIdx.x * 256 + threadIdx.x) * 4;
  const float4 v = *(const float4*)(src + e);
  ushort4 o;
  o.x = f2b(v.x); o.y = f2b(v.y); o.z = f2b(v.z); o.w = f2b(v.w);
  *(ushort4*)(dst + tix(e >> 8, e & 255)) = o;
}

// fp32 -> bf16 for the 12 weight/bias tensors, packed (linear layout)
__global__ __launch_bounds__(256) void cvt_w(
    const float* s0, const float* s1, const float* s2, const float* s3,
    const float* s4, const float* s5, const float* s6, const float* s7,
    const float* s8, const float* s9, const float* s10, const float* s11,
    u16* __restrict__ dst) {
  const int sizes[12] = {65536, 256, 65536, 256, 196608, 768,
                         65536, 256, 131072, 512, 131072, 256};
  const float* srcs[12] = {s0, s1, s2, s3, s4, s5, s6, s7, s8, s9, s10, s11};
  int gid = (blockIdx.x * 256 + threadIdx.x) * 4;
  if (gid >= W_TOTAL) return;
  int seg = 0, off = gid;
  while (off >= sizes[seg]) { off -= sizes[seg]; seg++; }
  const float4 v = *(const float4*)(srcs[seg] + off);
  ushort4 o;
  o.x = f2b(v.x); o.y = f2b(v.y); o.z = f2b(v.z); o.w = f2b(v.w);
  *(ushort4*)(dst + gid) = o;
}

// ---------------------------------------------------------------------------
// Edge aggregation: z = h + segment_sum(h[src], dst).  (tiled h/z)
// ---------------------------------------------------------------------------
#define SROWS_ 32   // rows per slice

__global__ __launch_bounds__(256) void agg_kernel(
    const u16* __restrict__ h, const int* __restrict__ esrc,
    const int* __restrict__ edst, u16* __restrict__ z) {
  __shared__ int s_src[EPG_];
  __shared__ int s_cnt[SROWS_];
  __shared__ int s_off[SROWS_ + 1];
  __shared__ int s_pos[SROWS_];
  const int g = blockIdx.x;
  const int r0 = blockIdx.y * SROWS_;
  const int t = threadIdx.x;

  if (t < SROWS_) s_cnt[t] = 0;
  __syncthreads();

  const int ebase = g * EPG_;
  int dl[4], sg[4];
#pragma unroll
  for (int i = 0; i < 4; i++) {
    const int e = ebase + t + i * 256;
    sg[i] = esrc[e];
    dl[i] = edst[e] - g * N_ - r0;
    if ((unsigned)dl[i] < SROWS_) atomicAdd(&s_cnt[dl[i]], 1);
  }
  __syncthreads();
  if (t == 0) {
    int acc = 0;
#pragma unroll
    for (int i = 0; i < SROWS_; i++) { s_off[i] = acc; acc += s_cnt[i]; }
    s_off[SROWS_] = acc;
  }
  __syncthreads();
  if (t < SROWS_) s_pos[t] = s_off[t];
  __syncthreads();
#pragma unroll
  for (int i = 0; i < 4; i++) {
    if ((unsigned)dl[i] < SROWS_) {
      const int slot = atomicAdd(&s_pos[dl[i]], 1);
      s_src[slot] = sg[i];
    }
  }
  __syncthreads();

  const int rg = t >> 5;
  const int c0 = (t & 31) * 8;
  for (int ib = 0; ib < SROWS_; ib += 8) {
    const int i = ib + rg;
    const int row = g * N_ + r0 + i;
    float acc[8];
    {
      const s16x8 v = *(const s16x8*)(h + tix(row, c0));
#pragma unroll
      for (int j = 0; j < 8; j++) acc[j] = b2f((u16)v[j]);
    }
    const int e0 = s_off[i], e1 = s_off[i + 1];
    for (int e = e0; e < e1; e++) {
      const int src = s_src[e];
      const s16x8 v = *(const s16x8*)(h + tix(src, c0));
#pragma unroll
      for (int j = 0; j < 8; j++) acc[j] += b2f((u16)v[j]);
    }
    s16x8 o;
#pragma unroll
    for (int j = 0; j < 8; j++) o[j] = (short)f2b(acc[j]);
    *(s16x8*)(z + tix(row, c0)) = o;
  }
}

// ---------------------------------------------------------------------------
// MFMA bf16 GEMM, 64x64 tile / BK=64 / 4 waves (2x2, wave-tile 32x32).
// EXACT round-5 body (best measured config: 2.27 TB/s aggregate). Grid is
// dim3(NCT, 1024) with col-tile in x (fastest): the NCT sharers of an A
// panel dispatch adjacently -> short-range L2 reuse. (r7 proved order is
// the BW lever: swapping dims kept FETCH identical and HALVED achieved BW.)
// ---------------------------------------------------------------------------
template <int NC, int K, int RELU, int RES, int STATS, int ASPLIT, int CMODE>
__global__ __launch_bounds__(256) void gemm_mfma(
    const u16* A, const u16* A2,
    const u16* __restrict__ W, const u16* __restrict__ bias,
    const u16* res, u16* C0, u16* C1, u16* C2,
    float* __restrict__ gsum, float* __restrict__ gsq) {
  __shared__ u16 As[2][64 * 64] __attribute__((aligned(16)));   // 8 KB each
  __shared__ u16 Bs[2][64 * 64] __attribute__((aligned(16)));

  const int t = threadIdx.x;
  const int wave = t >> 6, lane = t & 63;
  const int wr = wave >> 1, wc = wave & 1;
  const int quad = lane >> 4, ln15 = lane & 15;
  const int row0 = blockIdx.y * 64, col0 = blockIdx.x * 64;

  f32x4 acc[2][2];
#pragma unroll
  for (int i = 0; i < 2; i++)
#pragma unroll
    for (int j = 0; j < 2; j++) acc[i][j] = (f32x4){0.f, 0.f, 0.f, 0.f};

  // stage K-step kt into buffer b: 4 x 16B loads/thread (2 A + 2 B)
  auto stage = [&](int b, int kt) {
    const u16* Ab;
    int ksl;
    if (ASPLIT) {
      if (kt < 256) { Ab = A; ksl = kt >> 6; } else { Ab = A2; ksl = (kt - 256) >> 6; }
    } else {
      Ab = A; ksl = kt >> 6;
    }
    // 64-row half-panel of the tix row-block: contiguous 8 KB
    const u16* abase = Ab + ((size_t)(row0 >> 7) << 15) + (ksl << 13) +
                       ((row0 & 64) << 6);
#pragma unroll
    for (int i = 0; i < 2; i++) {
      const int fid = t + i * 256;            // 0..511
      glds16(abase + fid * 8, &As[b][fid * 8]);
      const int row = fid >> 3;               // 0..63 (C col)
      const int segp = (fid & 7) ^ (row & 7);
      glds16(W + (size_t)(col0 + row) * K + kt + segp * 8, &Bs[b][fid * 8]);
    }
  };

  stage(0, 0);
  for (int kt = 0; kt < K; kt += 64) {
    const int cur = (kt >> 6) & 1;
    if (kt + 64 < K) {
      stage(cur ^ 1, kt + 64);                         // prefetch next step
      asm volatile("s_waitcnt vmcnt(4)" ::: "memory"); // cur's 4 landed
    } else {
      asm volatile("s_waitcnt vmcnt(0)" ::: "memory");
    }
    __builtin_amdgcn_s_barrier();
#pragma unroll
    for (int ks = 0; ks < 64; ks += 32) {
      s16x8 af[2], bf[2];
#pragma unroll
      for (int i = 0; i < 2; i++) {
        const int ra = wr * 32 + i * 16 + ln15;
        af[i] = *(const s16x8*)(
            &As[cur][ra * 64 + ((((ks >> 3) + quad) ^ (ra & 7)) * 8)]);
      }
#pragma unroll
      for (int j = 0; j < 2; j++) {
        const int rb = wc * 32 + j * 16 + ln15;
        bf[j] = *(const s16x8*)(
            &Bs[cur][rb * 64 + ((((ks >> 3) + quad) ^ (rb & 7)) * 8)]);
      }
#pragma unroll
      for (int i = 0; i < 2; i++)
#pragma unroll
        for (int j = 0; j < 2; j++)
          acc[i][j] = __builtin_amdgcn_mfma_f32_16x16x32_bf16(af[i], bf[j], acc[i][j], 0, 0, 0);
    }
    __builtin_amdgcn_s_barrier();
  }

  // ---- epilogue (tiled C / res) ----
  const int cbase = col0 + wc * 32;   // + j*16 + ln15 = global col
  u16* Cb;
  int coff;
  if (CMODE) {
    const int chunk = col0 >> 8;
    Cb = (chunk == 0) ? C0 : ((chunk == 1) ? C1 : C2);
    coff = (col0 & 255) + wc * 32;
  } else {
    Cb = C0; coff = cbase;
  }

  float bs[2];
#pragma unroll
  for (int j = 0; j < 2; j++) bs[j] = b2f(bias[cbase + j * 16 + ln15]);

  float ssum[2] = {}, ssq[2] = {};
#pragma unroll
  for (int i = 0; i < 2; i++) {
    const int rbase = row0 + wr * 32 + i * 16 + quad * 4;
#pragma unroll
    for (int reg = 0; reg < 4; reg++) {
      const int row = rbase + reg;
#pragma unroll
      for (int j = 0; j < 2; j++) {
        float val = acc[i][j][reg] + bs[j];
        if (RELU) val = fmaxf(val, 0.f);
        if (RES) val += b2f(res[tix(row, cbase + j * 16 + ln15)]);
        Cb[tix(row, coff + j * 16 + ln15)] = f2b(val);
        if (STATS) { ssum[j] += val; ssq[j] += val * val; }
      }
    }
  }

  if (STATS) {
#pragma unroll
    for (int j = 0; j < 2; j++) {
      float s = ssum[j];
      s += __shfl_xor(s, 16);
      s += __shfl_xor(s, 32);
      float q = ssq[j];
      q += __shfl_xor(q, 16);
      q += __shfl_xor(q, 32);
      if (lane < 16) {
        atomicAdd(&gsum[cbase + j * 16 + lane], s);
        atomicAdd(&gsq[cbase + j * 16 + lane], q);
      }
    }
  }
}

// ---------------------------------------------------------------------------
// Fused 2-layer MLP (r11 = r10 + fully pipelined W staging, T3/T4 style):
//   COMBINE=0: x = A (glds16);  COMBINE=1: x = bn_l(A)+bn_a(Ara) (combine fold)
//   C = x + relu(x@W1^T + b1)@W2^T + b2 (+res), + stats.
// r10 diagnosis: 105 us both instances (GIN has HALF the FLOPs of FFN ->
// schedule-bound); 3 full vmcnt(0) drains per chunk were the stalls.
// r11: W2 split into FOUR 32-wide K-steps (16 KB = one Wst buffer) so it
// double-buffers like W1; every staging step issues into the dead buffer
// during the previous compute and waits with COUNTED vmcnt(4) (never 0
// mid-loop); next chunk's W1 prefetches during W2 step 3. W2's 32-u16-row
// layout swizzles with (row>>2)&3 -> 2 lanes/bank (free).
// LDS: xs 32K + tc 16K + Wst 32K = 80 KB -> 2 blocks/CU.
// ---------------------------------------------------------------------------
template <int CHUNKS, int RES_LDS, int COMBINE>
__global__ __launch_bounds__(256, 2) void fused_mlp(
    const u16* A, const u16* Ara,
    const u16* __restrict__ W1, const u16* __restrict__ b1,
    const u16* __restrict__ W2, const u16* __restrict__ b2,
    const u16* resg, u16* C, const float* __restrict__ st,
    float* __restrict__ gsum, float* __restrict__ gsq) {
  __shared__ u16 xs[4 * 64 * 64] __attribute__((aligned(16)));    // 32 KB
  __shared__ u16 tc[64 * 128] __attribute__((aligned(16)));       // 16 KB
  __shared__ u16 Wst[2][64 * 128] __attribute__((aligned(16)));   // 32 KB

  const int t = threadIdx.x;
  const int wave = t >> 6, lane = t & 63;
  const int wr = wave >> 1, wc = wave & 1;
  const int quad = lane >> 4, ln15 = lane & 15;
  const int row0 = blockIdx.x * 64;
  const int K2 = CHUNKS * 128;   // W2 row stride

  // W1 panel: 128 rows x 64 cols -> 16 KB, row stride 64 u16, (row&7) swizzle
  auto stage1 = [&](int b, int ch, int kt) {
#pragma unroll
    for (int i = 0; i < 4; i++) {
      const int fid = t + i * 256;      // 0..1023
      const int row = fid >> 3;         // 0..127
      const int segp = (fid & 7) ^ (row & 7);
      glds16(W1 + (size_t)(ch * 128 + row) * 256 + kt + segp * 8,
             &Wst[b][fid * 8]);
    }
  };
  // W2 K-step: 256 rows x 32 cols -> 16 KB, row stride 32 u16, (row>>2)&3 swz
  auto stageW2s = [&](int b, int ch, int ks) {
#pragma unroll
    for (int i = 0; i < 4; i++) {
      const int fid = t + i * 256;      // 0..1023
      const int row = fid >> 2;         // 0..255
      const int sg = fid & 3;
      const int segp = sg ^ ((row >> 2) & 3);
      glds16(W2 + (size_t)row * K2 + ch * 128 + ks * 32 + segp * 8,
             &Wst[b][fid * 8]);
    }
  };

  stage1(0, 0, 0);   // chunk 0's first W1 panel -> Wst[0]

  // ---- stage x rows row0..+63, all 256 cols (tiled: 4 contiguous 8K runs) --
  if (COMBINE) {
    // coeffs al|bl|aa|ba -> tc (as float[1024]); tc is dead until chunk 0
    float* cf = (float*)tc;
#pragma unroll
    for (int k = 0; k < 4; k++) cf[k * 256 + t] = st[1536 + k * 256 + t];
    __syncthreads();
    const size_t tbase = ((size_t)(row0 >> 7) << 15) + ((row0 & 64) << 6);
#pragma unroll
    for (int i = 0; i < 8; i++) {
      const int gid = t + i * 256;        // 0..2047 16B-chunks
      const int kstep = gid >> 9;
      const int fid = gid & 511;
      const size_t addr = tbase + kstep * 8192 + fid * 8;
      const s16x8 rl = *(const s16x8*)(A + addr);
      const s16x8 ra = *(const s16x8*)(Ara + addr);
      const int seg = (fid & 7) ^ ((fid >> 3) & 7);
      const int col = kstep * 64 + seg * 8;
      const float4 al0 = *(const float4*)(cf + col);
      const float4 al1 = *(const float4*)(cf + col + 4);
      const float4 bl0 = *(const float4*)(cf + 256 + col);
      const float4 bl1 = *(const float4*)(cf + 256 + col + 4);
      const float4 aa0 = *(const float4*)(cf + 512 + col);
      const float4 aa1 = *(const float4*)(cf + 512 + col + 4);
      const float4 ba0 = *(const float4*)(cf + 768 + col);
      const float4 ba1 = *(const float4*)(cf + 768 + col + 4);
      const float al[8] = {al0.x, al0.y, al0.z, al0.w, al1.x, al1.y, al1.z, al1.w};
      const float bl[8] = {bl0.x, bl0.y, bl0.z, bl0.w, bl1.x, bl1.y, bl1.z, bl1.w};
      const float aa[8] = {aa0.x, aa0.y, aa0.z, aa0.w, aa1.x, aa1.y, aa1.z, aa1.w};
      const float ba[8] = {ba0.x, ba0.y, ba0.z, ba0.w, ba1.x, ba1.y, ba1.z, ba1.w};
      s16x8 o;
#pragma unroll
      for (int j = 0; j < 8; j++)
        o[j] = (short)f2b(al[j] * b2f((u16)rl[j]) + bl[j] +
                          aa[j] * b2f((u16)ra[j]) + ba[j]);
      *(s16x8*)(xs + gid * 8) = o;
    }
    __syncthreads();   // xs ready (drains vmcnt too: W1 panel also landed)
  } else {
    const u16* abase = A + ((size_t)(row0 >> 7) << 15) + ((row0 & 64) << 6);
#pragma unroll
    for (int i = 0; i < 8; i++) {
      const int gid = t + i * 256;        // 0..2047 16B-loads
      const int kstep = gid >> 9;         // 512 loads per 8 KB panel
      const int fid = gid & 511;
      glds16(abase + kstep * 8192 + fid * 8, xs + gid * 8);
    }
    // no drain: chunk 0's first vmcnt(4) waits xs + W1 panel together
  }

  f32x4 acc2[2][8];
#pragma unroll
  for (int i = 0; i < 2; i++)
#pragma unroll
    for (int j = 0; j < 8; j++) acc2[i][j] = (f32x4){0.f, 0.f, 0.f, 0.f};

  // t-chunk LDS addressing: 128 cols = 16 segs of 16B; XOR low 3 seg bits
  // with row so 16-lane column-slice b128 reads are conflict-free.
  auto tca = [&](int row, int col) {
    const int s0 = col >> 3;
    return row * 128 + (((s0 & 8) | ((s0 ^ row) & 7)) << 3) + (col & 7);
  };

  for (int c = 0; c < CHUNKS; c++) {
    // ===== GEMM1: tchunk = relu(x @ W1[c*128..+128]^T), W1 dbuf pipelined ===
    f32x4 acc1[2][4];
#pragma unroll
    for (int i = 0; i < 2; i++)
#pragma unroll
      for (int j = 0; j < 4; j++) acc1[i][j] = (f32x4){0.f, 0.f, 0.f, 0.f};

    for (int kt = 0; kt < 256; kt += 64) {
      const int cur = (kt >> 6) & 1;
      if (kt < 192) {
        stage1(cur ^ 1, c, kt + 64);          // next W1 panel
      } else {
        stageW2s(0, c, 0);                    // W2 step0 into dead Wst[0]
      }
      asm volatile("s_waitcnt vmcnt(4)" ::: "memory");  // cur panel landed
      __builtin_amdgcn_s_barrier();
#pragma unroll
      for (int ks = 0; ks < 64; ks += 32) {
        s16x8 af[2], bf[4];
#pragma unroll
        for (int i = 0; i < 2; i++) {
          const int ra = wr * 32 + i * 16 + ln15;
          af[i] = *(const s16x8*)(
              &xs[(kt >> 6) * 4096 + ra * 64 +
                  ((((ks >> 3) + quad) ^ (ra & 7)) * 8)]);
        }
#pragma unroll
        for (int j = 0; j < 4; j++) {
          const int rb = wc * 64 + j * 16 + ln15;
          bf[j] = *(const s16x8*)(
              &Wst[cur][rb * 64 + ((((ks >> 3) + quad) ^ (rb & 7)) * 8)]);
        }
#pragma unroll
        for (int i = 0; i < 2; i++)
#pragma unroll
          for (int j = 0; j < 4; j++)
            acc1[i][j] = __builtin_amdgcn_mfma_f32_16x16x32_bf16(af[i], bf[j], acc1[i][j], 0, 0, 0);
      }
      __builtin_amdgcn_s_barrier();
    }

    stageW2s(1, c, 1);   // W2 step1 into Wst[1] (dead after kt=192's barrier)

    // relu + bias -> tc (bf16)
    {
      float b1s[4];
#pragma unroll
      for (int j = 0; j < 4; j++)
        b1s[j] = b2f(b1[c * 128 + wc * 64 + j * 16 + ln15]);
#pragma unroll
      for (int i = 0; i < 2; i++)
#pragma unroll
        for (int reg = 0; reg < 4; reg++) {
          const int rowl = wr * 32 + i * 16 + quad * 4 + reg;
#pragma unroll
          for (int j = 0; j < 4; j++) {
            const int coll = wc * 64 + j * 16 + ln15;
            tc[tca(rowl, coll)] = f2b(fmaxf(acc1[i][j][reg] + b1s[j], 0.f));
          }
        }
    }
    asm volatile("s_waitcnt lgkmcnt(0)" ::: "memory");  // tc writes visible
    asm volatile("s_waitcnt vmcnt(4)" ::: "memory");    // W2 step0 landed
    __builtin_amdgcn_s_barrier();

    // ===== GEMM2: acc2 += tchunk @ W2[:, c*128..+128]^T, 4 dbuf'd K-steps ===
#pragma unroll
    for (int s = 0; s < 4; s++) {
      s16x8 af[2], bf[8];
#pragma unroll
      for (int i = 0; i < 2; i++) {
        const int ra = wr * 32 + i * 16 + ln15;
        af[i] = *(const s16x8*)(&tc[tca(ra, s * 32 + quad * 8)]);
      }
#pragma unroll
      for (int j = 0; j < 8; j++) {
        const int rb = wc * 128 + j * 16 + ln15;
        bf[j] = *(const s16x8*)(
            &Wst[s & 1][rb * 32 + ((quad ^ ((rb >> 2) & 3)) * 8)]);
      }
#pragma unroll
      for (int i = 0; i < 2; i++)
#pragma unroll
        for (int j = 0; j < 8; j++)
          acc2[i][j] = __builtin_amdgcn_mfma_f32_16x16x32_bf16(af[i], bf[j], acc2[i][j], 0, 0, 0);
      __builtin_amdgcn_s_barrier();           // done reading Wst[s&1]
      if (s == 0) {
        stageW2s(0, c, 2);                    // step2 -> Wst[0]
        asm volatile("s_waitcnt vmcnt(4)" ::: "memory");  // step1 landed
        __builtin_amdgcn_s_barrier();
      } else if (s == 1) {
        stageW2s(1, c, 3);                    // step3 -> Wst[1]
        asm volatile("s_waitcnt vmcnt(4)" ::: "memory");  // step2 landed
        __builtin_amdgcn_s_barrier();
      } else if (s == 2) {
        if (c + 1 < CHUNKS) {
          stage1(0, c + 1, 0);                // next chunk's W1 -> Wst[0]
          asm volatile("s_waitcnt vmcnt(4)" ::: "memory");  // step3 landed
        } else {
          asm volatile("s_waitcnt vmcnt(0)" ::: "memory");
        }
        __builtin_amdgcn_s_barrier();
      }
      // s == 3: end-of-chunk barrier above protects Wst reuse next chunk
    }
  }

  // ---- epilogue: y = acc2 + b2 + res -> C (tiled) + stats ----
  float bs2[8];
#pragma unroll
  for (int j = 0; j < 8; j++)
    bs2[j] = b2f(b2[wc * 128 + j * 16 + ln15]);

  float ssum[8] = {}, ssq[8] = {};
#pragma unroll
  for (int i = 0; i < 2; i++) {
#pragma unroll
    for (int reg = 0; reg < 4; reg++) {
      const int rowl = wr * 32 + i * 16 + quad * 4 + reg;
      const int row = row0 + rowl;
#pragma unroll
      for (int j = 0; j < 8; j++) {
        const int col = wc * 128 + j * 16 + ln15;
        float val = acc2[i][j][reg] + bs2[j];
        if (RES_LDS) {
          val += b2f(xs[(col >> 6) * 4096 + rowl * 64 +
                        ((((col >> 3) & 7) ^ (rowl & 7)) << 3) + (col & 7)]);
        } else {
          val += b2f(resg[tix(row, col)]);
        }
        C[tix(row, col)] = f2b(val);
        ssum[j] += val; ssq[j] += val * val;
      }
    }
  }

#pragma unroll
  for (int j = 0; j < 8; j++) {
    float s = ssum[j];
    s += __shfl_xor(s, 16);
    s += __shfl_xor(s, 32);
    float q = ssq[j];
    q += __shfl_xor(q, 16);
    q += __shfl_xor(q, 32);
    if (lane < 16) {
      atomicAdd(&gsum[wc * 128 + j * 16 + lane], s);
      atomicAdd(&gsq[wc * 128 + j * 16 + lane], q);
    }
  }
}

// ---------------------------------------------------------------------------
// MFMA attention: one block per (graph, head), 4 waves; q/k/v/o tiled (tix).
// ---------------------------------------------------------------------------
__global__ __launch_bounds__(256) void attn_mfma(
    const u16* q, const u16* __restrict__ k,
    const u16* __restrict__ v, u16* o) {
  __shared__ u16 lds[21760] __attribute__((aligned(16)));
  u16* Vt = lds;                   // [32][136]  V transposed (d-major)
  u16* Qs = lds + 4352;            // [128][40]  scaled Q
  u16* Ks = lds + 4352 + 5120;     // [128][40]
  u16* P  = lds + 4352;            // [128][136] aliases Qs/Ks after barrier

  const int g = blockIdx.x >> 3;
  const int hd = blockIdx.x & 7;
  const int t = threadIdx.x;
  const int wave = t >> 6, lane = t & 63;
  const int quad = lane >> 4, ln15 = lane & 15;
  const int strip = wave * 32;
  const float scale = 0.1767766952966369f;  // 1/sqrt(32)

  // ---- stage Q (pre-scaled), K, V^T ----
#pragma unroll
  for (int i = 0; i < 4; i++) {
    const int fid = t + i * 256;   // 0..1023
    const int row = fid >> 3;
    const int seg = fid & 7;       // 4 u16 each
    const int gidx = tix(g * N_ + row, hd * HD_ + seg * 4);
    const ushort4 qv = *(const ushort4*)(q + gidx);
    const ushort4 kv = *(const ushort4*)(k + gidx);
    const ushort4 vv = *(const ushort4*)(v + gidx);
    ushort4 qs;
    qs.x = f2b(b2f(qv.x) * scale); qs.y = f2b(b2f(qv.y) * scale);
    qs.z = f2b(b2f(qv.z) * scale); qs.w = f2b(b2f(qv.w) * scale);
    *(ushort4*)(Qs + row * 40 + seg * 4) = qs;
    *(ushort4*)(Ks + row * 40 + seg * 4) = kv;
    Vt[(seg * 4 + 0) * 136 + row] = vv.x;
    Vt[(seg * 4 + 1) * 136 + row] = vv.y;
    Vt[(seg * 4 + 2) * 136 + row] = vv.z;
    Vt[(seg * 4 + 3) * 136 + row] = vv.w;
  }
  __syncthreads();

  // ---- S = Q K^T (strip x 128) ----
  s16x8 af[2], bf[8];
#pragma unroll
  for (int mi = 0; mi < 2; mi++)
    af[mi] = *(const s16x8*)(Qs + (strip + mi * 16 + ln15) * 40 + quad * 8);
#pragma unroll
  for (int nj = 0; nj < 8; nj++)
    bf[nj] = *(const s16x8*)(Ks + (nj * 16 + ln15) * 40 + quad * 8);

  f32x4 acc[2][8];
#pragma unroll
  for (int mi = 0; mi < 2; mi++)
#pragma unroll
    for (int nj = 0; nj < 8; nj++)
      acc[mi][nj] = __builtin_amdgcn_mfma_f32_16x16x32_bf16(
          af[mi], bf[nj], (f32x4){0.f, 0.f, 0.f, 0.f}, 0, 0, 0);

  __syncthreads();  // Q/K dead; region becomes P

  // ---- softmax per row, write P ----
#pragma unroll
  for (int mi = 0; mi < 2; mi++) {
#pragma unroll
    for (int reg = 0; reg < 4; reg++) {
      float mx = acc[mi][0][reg];
#pragma unroll
      for (int j = 1; j < 8; j++) mx = fmaxf(mx, acc[mi][j][reg]);
      mx = fmaxf(mx, __shfl_xor(mx, 1));
      mx = fmaxf(mx, __shfl_xor(mx, 2));
      mx = fmaxf(mx, __shfl_xor(mx, 4));
      mx = fmaxf(mx, __shfl_xor(mx, 8));
      float e[8], s = 0.f;
#pragma unroll
      for (int j = 0; j < 8; j++) { e[j] = __expf(acc[mi][j][reg] - mx); s += e[j]; }
      s += __shfl_xor(s, 1);
      s += __shfl_xor(s, 2);
      s += __shfl_xor(s, 4);
      s += __shfl_xor(s, 8);
      const float inv = 1.f / s;
      const int prow = strip + mi * 16 + quad * 4 + reg;
#pragma unroll
      for (int j = 0; j < 8; j++)
        P[prow * 136 + j * 16 + ln15] = f2b(e[j] * inv);
    }
  }
  __syncthreads();

  // ---- O = P V (strip x 32) ----
  f32x4 acc2[2][2];
#pragma unroll
  for (int mi = 0; mi < 2; mi++)
#pragma unroll
    for (int nj = 0; nj < 2; nj++) acc2[mi][nj] = (f32x4){0.f, 0.f, 0.f, 0.f};
#pragma unroll
  for (int kt = 0; kt < 4; kt++) {
    s16x8 paf[2], vbf[2];
#pragma unroll
    for (int mi = 0; mi < 2; mi++)
      paf[mi] = *(const s16x8*)(P + (strip + mi * 16 + ln15) * 136 + kt * 32 + quad * 8);
#pragma unroll
    for (int nj = 0; nj < 2; nj++)
      vbf[nj] = *(const s16x8*)(Vt + (nj * 16 + ln15) * 136 + kt * 32 + quad * 8);
#pragma unroll
    for (int mi = 0; mi < 2; mi++)
#pragma unroll
      for (int nj = 0; nj < 2; nj++)
        acc2[mi][nj] = __builtin_amdgcn_mfma_f32_16x16x32_bf16(
            paf[mi], vbf[nj], acc2[mi][nj], 0, 0, 0);
  }

#pragma unroll
  for (int mi = 0; mi < 2; mi++)
#pragma unroll
    for (int nj = 0; nj < 2; nj++)
#pragma unroll
      for (int reg = 0; reg < 4; reg++) {
        const int row = strip + mi * 16 + quad * 4 + reg;
        o[tix(g * N_ + row, hd * HD_ + nj * 16 + ln15)] =
            f2b(acc2[mi][nj][reg]);
      }
}

// BN finalize: a = g*rsqrt(var+eps); b' = b - mean*a   (fp32 params)
__global__ void bn_finalize(const float* __restrict__ sum,
                            const float* __restrict__ sq,
                            const float* __restrict__ g,
                            const float* __restrict__ bb,
                            float* __restrict__ a, float* __restrict__ b) {
  const int c = threadIdx.x;
  const float mean = sum[c] * (1.f / R_);
  const float var = fmaxf(sq[c] * (1.f / R_) - mean * mean, 0.f);
  const float ai = g[c] * rsqrtf(var + 1e-5f);
  a[c] = ai;
  b[c] = bb[c] - mean * ai;
}

// out = bn_out(y): tiled bf16 y -> linear fp32 out
__global__ __launch_bounds__(256) void final_kernel(
    const u16* __restrict__ y, const float* __restrict__ st,
    float* __restrict__ out) {
  const int e = (blockIdx.x * 256 + threadIdx.x) * 4;
  const int col = e & 255;
  float y4[4];
  ld4b(y + tix(e >> 8, col), y4);
  const float* ao = st + 2560;
  const float* bo = st + 2816;
  float4 o;
  o.x = ao[col + 0] * y4[0] + bo[col + 0];
  o.y = ao[col + 1] * y4[1] + bo[col + 1];
  o.z = ao[col + 2] * y4[2] + bo[col + 2];
  o.w = ao[col + 3] * y4[3] + bo[col + 3];
  *(float4*)(out + e) = o;
}

extern "C" void kernel_launch(void* const* d_in, const int* in_sizes, int n_in,
                              void* d_out, int out_size, void* d_ws, size_t ws_size,
                              hipStream_t stream) {
  const float* h = (const float*)d_in[0];
  const int* esrc = (const int*)d_in[1];
  const int* edst = (const int*)d_in[2];
  const float* bn_local_g = (const float*)d_in[11];
  const float* bn_local_b = (const float*)d_in[12];
  const float* bn_attn_g = (const float*)d_in[13];
  const float* bn_attn_b = (const float*)d_in[14];
  const float* bn_out_g = (const float*)d_in[15];
  const float* bn_out_b = (const float*)d_in[16];

  const size_t RH = (size_t)R_ * H_;
  float* stats = (float*)d_ws;                        // 3072 floats
  u16* WB = (u16*)((char*)d_ws + 65536);              // packed bf16 weights ~1.3 MB
  u16* Hb = (u16*)((char*)d_ws + 65536 + 2097152);    // h in bf16 (tiled), 32 MB
  u16* S1 = Hb + RH;                                  // 32 MB
  u16* S2 = S1 + RH;                                  // 32 MB
  u16* OD = (u16*)d_out;                              // first 32 MB of d_out as bf16 scratch
  float* outf = (float*)d_out;                        // final fp32 out (64 MB)

  zero_stats<<<12, 256, 0, stream>>>(stats);
  cvt_h<<<(int)(RH / 4 / 256), 256, 0, stream>>>(h, Hb);
  cvt_w<<<(W_TOTAL / 4 + 255) / 256, 256, 0, stream>>>(
      (const float*)d_in[3], (const float*)d_in[4], (const float*)d_in[5],
      (const float*)d_in[6], (const float*)d_in[7], (const float*)d_in[8],
      (const float*)d_in[9], (const float*)d_in[10], (const float*)d_in[17],
      (const float*)d_in[18], (const float*)d_in[19], (const float*)d_in[20], WB);

  // qkv fused: [R,768] -> q=S1, k=S2, v=OD
  gemm_mfma<768, 256, 0, 0, 0, 0, 1><<<dim3(12, 1024), 256, 0, stream>>>(
      Hb, nullptr, WB + OFF_AIW, WB + OFF_AIB, nullptr, S1, S2, OD,
      nullptr, nullptr);
  // o = softmax(q k^T / sqrt(32)) v, in-place over q (S1)
  attn_mfma<<<B_ * NH_, 256, 0, stream>>>(S1, S2, OD, S1);
  // r_attn = h + o@Wo^T -> S2, + stats_attn
  gemm_mfma<256, 256, 0, 1, 1, 0, 0><<<dim3(4, 1024), 256, 0, stream>>>(
      S1, nullptr, WB + OFF_AOW, WB + OFF_AOB, Hb, S2, nullptr, nullptr,
      stats + 512, stats + 768);
  // z = h + segment_sum -> OD
  agg_kernel<<<dim3(B_, 4), 256, 0, stream>>>(Hb, esrc, edst, OD);
  // r_local = h + relu(z@GW1+b1)@GW2+b2 -> OD in place, + stats_local
  fused_mlp<2, 0, 0><<<1024, 256, 0, stream>>>(
      OD, nullptr, WB + OFF_GW1, WB + OFF_GB1, WB + OFF_GW2, WB + OFF_GB2,
      Hb, OD, nullptr, stats + 0, stats + 256);

  bn_finalize<<<1, 256, 0, stream>>>(stats + 0, stats + 256, bn_local_g,
                                     bn_local_b, stats + 1536, stats + 1792);
  bn_finalize<<<1, 256, 0, stream>>>(stats + 512, stats + 768, bn_attn_g,
                                     bn_attn_b, stats + 2048, stats + 2304);

  // y = x + relu(x@F1+b1)@F2+b2 -> S1, x = bn_l(OD)+bn_a(S2) computed in the
  // x-stage (combine kernel folded in), + stats_out
  fused_mlp<4, 1, 1><<<1024, 256, 0, stream>>>(
      OD, S2, WB + OFF_F1W, WB + OFF_F1B, WB + OFF_F2W, WB + OFF_F2B,
      nullptr, S1, stats, stats + 1024, stats + 1280);

  bn_finalize<<<1, 256, 0, stream>>>(stats + 1024, stats + 1280, bn_out_g,
                                     bn_out_b, stats + 2560, stats + 2816);
  // out = bn_out(y S1) -> fp32 d_out
  final_kernel<<<(int)(RH / 4 / 256), 256, 0, stream>>>(S1, stats, outf);
}

// Round 12
// 535.786 us; speedup vs baseline: 1.0207x; 1.0207x over previous
//
#include <hip/hip_runtime.h>
#include <hip/hip_bf16.h>

#define B_   512
#define N_   128
#define H_   256
#define NH_  8
#define HD_  32
#define DEG_ 8
#define R_   (B_ * N_)          // 65536 rows
#define E_   (B_ * N_ * DEG_)   // 524288 edges
#define EPG_ (N_ * DEG_)        // 1024 edges per graph

typedef unsigned short u16;
typedef unsigned int u32;

typedef __attribute__((ext_vector_type(8))) short s16x8;   // 8 bf16 = 4 VGPRs
typedef __attribute__((ext_vector_type(4))) float f32x4;   // MFMA acc

__device__ __forceinline__ float b2f(u16 u) {
  union { u32 i; float f; } v;
  v.i = ((u32)u) << 16;
  return v.f;
}
__device__ __forceinline__ u16 f2b(float f) {
  union { float f; u32 u; } v;
  v.f = f;
  u32 r = (v.u + 0x7fffu + ((v.u >> 16) & 1u)) >> 16;  // RNE
  return (u16)r;
}
__device__ __forceinline__ void ld4b(const u16* p, float* o) {
  ushort4 v = *(const ushort4*)p;
  o[0] = b2f(v.x); o[1] = b2f(v.y); o[2] = b2f(v.z); o[3] = b2f(v.w);
}

// ---------------------------------------------------------------------------
// Tiled-swizzled layout for ALL 256-col bf16 intermediates:
//   [rowblk=row>>7][kstep=col>>6][row&127][seg: ((col>>3)&7)^(row&7)][col&7]
// A 64-row x 64-col panel is one contiguous 8 KB run -> GEMM A-staging is a
// pure linear burst; the LDS XOR swizzle is pre-baked at every producer.
// ---------------------------------------------------------------------------
__device__ __forceinline__ int tix(int row, int col) {
  return ((row >> 7) << 15) + (((col >> 6) & 3) << 13) + ((row & 127) << 6) +
         (((((col >> 3) & 7) ^ (row & 7))) << 3) + (col & 7);
}

__device__ __forceinline__ void glds16(const u16* g, u16* l) {
  __builtin_amdgcn_global_load_lds(
      (const __attribute__((address_space(1))) void*)g,
      (__attribute__((address_space(3))) void*)l, 16, 0, 0);
}

// stats layout (floats, at d_ws + 0):
//   0..255 sum_local | 256..511 sq_local | 512..767 sum_attn | 768..1023 sq_attn
//   1024..1279 sum_out | 1280..1535 sq_out
//   1536 a_local | 1792 b_local | 2048 a_attn | 2304 b_attn | 2560 a_out | 2816 b_out

// packed bf16 weight area offsets (u16 elements)
#define OFF_GW1 0
#define OFF_GB1 65536
#define OFF_GW2 65792
#define OFF_GB2 131328
#define OFF_AIW 131584
#define OFF_AIB 328192
#define OFF_AOW 328960
#define OFF_AOB 394496
#define OFF_F1W 394752
#define OFF_F1B 525824
#define OFF_F2W 526336
#define OFF_F2B 657408
#define W_TOTAL 657664

__global__ void zero_stats(float* __restrict__ st) {
  st[blockIdx.x * 256 + threadIdx.x] = 0.f;
}

// fp32 (linear) -> bf16 (tiled) for h
__global__ __launch_bounds__(256) void cvt_h(const float* __restrict__ src,
                                             u16* __restrict__ dst) {
  const int e = (blockIdx.x * 256 + threadIdx.x) * 4;
  const float4 v = *(const float4*)(src + e);
  ushort4 o;
  o.x = f2b(v.x); o.y = f2b(v.y); o.z = f2b(v.z); o.w = f2b(v.w);
  *(ushort4*)(dst + tix(e >> 8, e & 255)) = o;
}

// fp32 -> bf16 for the 12 weight/bias tensors, packed (linear layout)
__global__ __launch_bounds__(256) void cvt_w(
    const float* s0, const float* s1, const float* s2, const float* s3,
    const float* s4, const float* s5, const float* s6, const float* s7,
    const float* s8, const float* s9, const float* s10, const float* s11,
    u16* __restrict__ dst) {
  const int sizes[12] = {65536, 256, 65536, 256, 196608, 768,
                         65536, 256, 131072, 512, 131072, 256};
  const float* srcs[12] = {s0, s1, s2, s3, s4, s5, s6, s7, s8, s9, s10, s11};
  int gid = (blockIdx.x * 256 + threadIdx.x) * 4;
  if (gid >= W_TOTAL) return;
  int seg = 0, off = gid;
  while (off >= sizes[seg]) { off -= sizes[seg]; seg++; }
  const float4 v = *(const float4*)(srcs[seg] + off);
  ushort4 o;
  o.x = f2b(v.x); o.y = f2b(v.y); o.z = f2b(v.z); o.w = f2b(v.w);
  *(ushort4*)(dst + gid) = o;
}

// ---------------------------------------------------------------------------
// Edge aggregation: z = h + segment_sum(h[src], dst).  (tiled h/z)
// ---------------------------------------------------------------------------
#define SROWS_ 32   // rows per slice

__global__ __launch_bounds__(256) void agg_kernel(
    const u16* __restrict__ h, const int* __restrict__ esrc,
    const int* __restrict__ edst, u16* __restrict__ z) {
  __shared__ int s_src[EPG_];
  __shared__ int s_cnt[SROWS_];
  __shared__ int s_off[SROWS_ + 1];
  __shared__ int s_pos[SROWS_];
  const int g = blockIdx.x;
  const int r0 = blockIdx.y * SROWS_;
  const int t = threadIdx.x;

  if (t < SROWS_) s_cnt[t] = 0;
  __syncthreads();

  const int ebase = g * EPG_;
  int dl[4], sg[4];
#pragma unroll
  for (int i = 0; i < 4; i++) {
    const int e = ebase + t + i * 256;
    sg[i] = esrc[e];
    dl[i] = edst[e] - g * N_ - r0;
    if ((unsigned)dl[i] < SROWS_) atomicAdd(&s_cnt[dl[i]], 1);
  }
  __syncthreads();
  if (t == 0) {
    int acc = 0;
#pragma unroll
    for (int i = 0; i < SROWS_; i++) { s_off[i] = acc; acc += s_cnt[i]; }
    s_off[SROWS_] = acc;
  }
  __syncthreads();
  if (t < SROWS_) s_pos[t] = s_off[t];
  __syncthreads();
#pragma unroll
  for (int i = 0; i < 4; i++) {
    if ((unsigned)dl[i] < SROWS_) {
      const int slot = atomicAdd(&s_pos[dl[i]], 1);
      s_src[slot] = sg[i];
    }
  }
  __syncthreads();

  const int rg = t >> 5;
  const int c0 = (t & 31) * 8;
  for (int ib = 0; ib < SROWS_; ib += 8) {
    const int i = ib + rg;
    const int row = g * N_ + r0 + i;
    float acc[8];
    {
      const s16x8 v = *(const s16x8*)(h + tix(row, c0));
#pragma unroll
      for (int j = 0; j < 8; j++) acc[j] = b2f((u16)v[j]);
    }
    const int e0 = s_off[i], e1 = s_off[i + 1];
    for (int e = e0; e < e1; e++) {
      const int src = s_src[e];
      const s16x8 v = *(const s16x8*)(h + tix(src, c0));
#pragma unroll
      for (int j = 0; j < 8; j++) acc[j] += b2f((u16)v[j]);
    }
    s16x8 o;
#pragma unroll
    for (int j = 0; j < 8; j++) o[j] = (short)f2b(acc[j]);
    *(s16x8*)(z + tix(row, c0)) = o;
  }
}

// ---------------------------------------------------------------------------
// MFMA bf16 GEMM, 64x64 tile / BK=64 / 4 waves (2x2, wave-tile 32x32).
// EXACT round-5 body. Grid dim3(NCT, 1024), col-tile fastest (L2 reuse).
// ---------------------------------------------------------------------------
template <int NC, int K, int RELU, int RES, int STATS, int ASPLIT, int CMODE>
__global__ __launch_bounds__(256) void gemm_mfma(
    const u16* A, const u16* A2,
    const u16* __restrict__ W, const u16* __restrict__ bias,
    const u16* res, u16* C0, u16* C1, u16* C2,
    float* __restrict__ gsum, float* __restrict__ gsq) {
  __shared__ u16 As[2][64 * 64] __attribute__((aligned(16)));   // 8 KB each
  __shared__ u16 Bs[2][64 * 64] __attribute__((aligned(16)));

  const int t = threadIdx.x;
  const int wave = t >> 6, lane = t & 63;
  const int wr = wave >> 1, wc = wave & 1;
  const int quad = lane >> 4, ln15 = lane & 15;
  const int row0 = blockIdx.y * 64, col0 = blockIdx.x * 64;

  f32x4 acc[2][2];
#pragma unroll
  for (int i = 0; i < 2; i++)
#pragma unroll
    for (int j = 0; j < 2; j++) acc[i][j] = (f32x4){0.f, 0.f, 0.f, 0.f};

  auto stage = [&](int b, int kt) {
    const u16* Ab;
    int ksl;
    if (ASPLIT) {
      if (kt < 256) { Ab = A; ksl = kt >> 6; } else { Ab = A2; ksl = (kt - 256) >> 6; }
    } else {
      Ab = A; ksl = kt >> 6;
    }
    const u16* abase = Ab + ((size_t)(row0 >> 7) << 15) + (ksl << 13) +
                       ((row0 & 64) << 6);
#pragma unroll
    for (int i = 0; i < 2; i++) {
      const int fid = t + i * 256;            // 0..511
      glds16(abase + fid * 8, &As[b][fid * 8]);
      const int row = fid >> 3;               // 0..63 (C col)
      const int segp = (fid & 7) ^ (row & 7);
      glds16(W + (size_t)(col0 + row) * K + kt + segp * 8, &Bs[b][fid * 8]);
    }
  };

  stage(0, 0);
  for (int kt = 0; kt < K; kt += 64) {
    const int cur = (kt >> 6) & 1;
    if (kt + 64 < K) {
      stage(cur ^ 1, kt + 64);
      asm volatile("s_waitcnt vmcnt(4)" ::: "memory");
    } else {
      asm volatile("s_waitcnt vmcnt(0)" ::: "memory");
    }
    __builtin_amdgcn_s_barrier();
#pragma unroll
    for (int ks = 0; ks < 64; ks += 32) {
      s16x8 af[2], bf[2];
#pragma unroll
      for (int i = 0; i < 2; i++) {
        const int ra = wr * 32 + i * 16 + ln15;
        af[i] = *(const s16x8*)(
            &As[cur][ra * 64 + ((((ks >> 3) + quad) ^ (ra & 7)) * 8)]);
      }
#pragma unroll
      for (int j = 0; j < 2; j++) {
        const int rb = wc * 32 + j * 16 + ln15;
        bf[j] = *(const s16x8*)(
            &Bs[cur][rb * 64 + ((((ks >> 3) + quad) ^ (rb & 7)) * 8)]);
      }
#pragma unroll
      for (int i = 0; i < 2; i++)
#pragma unroll
        for (int j = 0; j < 2; j++)
          acc[i][j] = __builtin_amdgcn_mfma_f32_16x16x32_bf16(af[i], bf[j], acc[i][j], 0, 0, 0);
    }
    __builtin_amdgcn_s_barrier();
  }

  // ---- epilogue (tiled C / res) ----
  const int cbase = col0 + wc * 32;
  u16* Cb;
  int coff;
  if (CMODE) {
    const int chunk = col0 >> 8;
    Cb = (chunk == 0) ? C0 : ((chunk == 1) ? C1 : C2);
    coff = (col0 & 255) + wc * 32;
  } else {
    Cb = C0; coff = cbase;
  }

  float bs[2];
#pragma unroll
  for (int j = 0; j < 2; j++) bs[j] = b2f(bias[cbase + j * 16 + ln15]);

  float ssum[2] = {}, ssq[2] = {};
#pragma unroll
  for (int i = 0; i < 2; i++) {
    const int rbase = row0 + wr * 32 + i * 16 + quad * 4;
#pragma unroll
    for (int reg = 0; reg < 4; reg++) {
      const int row = rbase + reg;
#pragma unroll
      for (int j = 0; j < 2; j++) {
        float val = acc[i][j][reg] + bs[j];
        if (RELU) val = fmaxf(val, 0.f);
        if (RES) val += b2f(res[tix(row, cbase + j * 16 + ln15)]);
        Cb[tix(row, coff + j * 16 + ln15)] = f2b(val);
        if (STATS) { ssum[j] += val; ssq[j] += val * val; }
      }
    }
  }

  if (STATS) {
#pragma unroll
    for (int j = 0; j < 2; j++) {
      float s = ssum[j];
      s += __shfl_xor(s, 16);
      s += __shfl_xor(s, 32);
      float q = ssq[j];
      q += __shfl_xor(q, 16);
      q += __shfl_xor(q, 32);
      if (lane < 16) {
        atomicAdd(&gsum[cbase + j * 16 + lane], s);
        atomicAdd(&gsq[cbase + j * 16 + lane], q);
      }
    }
  }
}

// ---------------------------------------------------------------------------
// QKV GEMM (r12): one block computes q, k AND v 64-col tiles for its
// (row-tile, col&255) position — the A panel is staged ONCE instead of 3x
// (the three outputs share identical A). Grid dim3(4, 1024); 4096 blocks vs
// 12288. Per kt step: 2 A + 6 B loads/thread, counted vmcnt(8) dbuf.
// LDS = As 16K + Bs 48K = 64 KB -> 2 blocks/CU. acc 3x2x2 f32x4 = 48 VGPR.
// Weight row for output o (0=q,1=k,2=v), col c: W[o*256 + c].
// ---------------------------------------------------------------------------
__global__ __launch_bounds__(256) void qkv_mfma(
    const u16* A, const u16* __restrict__ W, const u16* __restrict__ bias,
    u16* Cq, u16* Ck, u16* Cv) {
  __shared__ u16 As[2][64 * 64] __attribute__((aligned(16)));      // 16 KB
  __shared__ u16 Bs[2][3 * 64 * 64] __attribute__((aligned(16)));  // 48 KB

  const int t = threadIdx.x;
  const int wave = t >> 6, lane = t & 63;
  const int wr = wave >> 1, wc = wave & 1;
  const int quad = lane >> 4, ln15 = lane & 15;
  const int row0 = blockIdx.y * 64, col0 = blockIdx.x * 64;

  f32x4 acc[3][2][2];
#pragma unroll
  for (int o = 0; o < 3; o++)
#pragma unroll
    for (int i = 0; i < 2; i++)
#pragma unroll
      for (int j = 0; j < 2; j++) acc[o][i][j] = (f32x4){0.f, 0.f, 0.f, 0.f};

  auto stage = [&](int b, int kt) {
    const u16* abase = A + ((size_t)(row0 >> 7) << 15) + ((kt >> 6) << 13) +
                       ((row0 & 64) << 6);
#pragma unroll
    for (int i = 0; i < 2; i++) {
      const int fid = t + i * 256;            // 0..511
      glds16(abase + fid * 8, &As[b][fid * 8]);
    }
#pragma unroll
    for (int o = 0; o < 3; o++)
#pragma unroll
      for (int i = 0; i < 2; i++) {
        const int fid = t + i * 256;
        const int row = fid >> 3;             // 0..63 (output col)
        const int segp = (fid & 7) ^ (row & 7);
        glds16(W + (size_t)(o * 256 + col0 + row) * 256 + kt + segp * 8,
               &Bs[b][o * 4096 + fid * 8]);
      }
  };

  stage(0, 0);
  for (int kt = 0; kt < 256; kt += 64) {
    const int cur = (kt >> 6) & 1;
    if (kt + 64 < 256) {
      stage(cur ^ 1, kt + 64);                         // +8 loads in flight
      asm volatile("s_waitcnt vmcnt(8)" ::: "memory"); // cur's 8 landed
    } else {
      asm volatile("s_waitcnt vmcnt(0)" ::: "memory");
    }
    __builtin_amdgcn_s_barrier();
#pragma unroll
    for (int ks = 0; ks < 64; ks += 32) {
      s16x8 af[2];
#pragma unroll
      for (int i = 0; i < 2; i++) {
        const int ra = wr * 32 + i * 16 + ln15;
        af[i] = *(const s16x8*)(
            &As[cur][ra * 64 + ((((ks >> 3) + quad) ^ (ra & 7)) * 8)]);
      }
#pragma unroll
      for (int o = 0; o < 3; o++) {
        s16x8 bf[2];
#pragma unroll
        for (int j = 0; j < 2; j++) {
          const int rb = wc * 32 + j * 16 + ln15;
          bf[j] = *(const s16x8*)(
              &Bs[cur][o * 4096 + rb * 64 + ((((ks >> 3) + quad) ^ (rb & 7)) * 8)]);
        }
#pragma unroll
        for (int i = 0; i < 2; i++)
#pragma unroll
          for (int j = 0; j < 2; j++)
            acc[o][i][j] = __builtin_amdgcn_mfma_f32_16x16x32_bf16(af[i], bf[j], acc[o][i][j], 0, 0, 0);
      }
    }
    __builtin_amdgcn_s_barrier();
  }

  // ---- epilogue: three 256-col tiled outputs ----
  const int cbase = col0 + wc * 32;
#pragma unroll
  for (int o = 0; o < 3; o++) {
    u16* Co = (o == 0) ? Cq : ((o == 1) ? Ck : Cv);
    float bs[2];
#pragma unroll
    for (int j = 0; j < 2; j++) bs[j] = b2f(bias[o * 256 + cbase + j * 16 + ln15]);
#pragma unroll
    for (int i = 0; i < 2; i++) {
      const int rbase = row0 + wr * 32 + i * 16 + quad * 4;
#pragma unroll
      for (int reg = 0; reg < 4; reg++) {
        const int row = rbase + reg;
#pragma unroll
        for (int j = 0; j < 2; j++)
          Co[tix(row, cbase + j * 16 + ln15)] = f2b(acc[o][i][j][reg] + bs[j]);
      }
    }
  }
}

// ---------------------------------------------------------------------------
// Fused 2-layer MLP (r10-exact body, best measured 545.7 us total):
//   COMBINE=0: x = A (glds16);  COMBINE=1: x = bn_l(A)+bn_a(Ara) (combine fold)
//   C = x + relu(x@W1^T + b1)@W2^T + b2 (+res), + stats.
// r9: weights MUST stage via wave-linear glds16 (direct loads 2x'd time).
// r11: pipelined W staging was NEUTRAL and 5x'd bank conflicts -> reverted.
// LDS: xs 32K + tc 16K + Wst 32K = 80 KB -> 2 blocks/CU.
// ---------------------------------------------------------------------------
template <int CHUNKS, int RES_LDS, int COMBINE>
__global__ __launch_bounds__(256, 2) void fused_mlp(
    const u16* A, const u16* Ara,
    const u16* __restrict__ W1, const u16* __restrict__ b1,
    const u16* __restrict__ W2, const u16* __restrict__ b2,
    const u16* resg, u16* C, const float* __restrict__ st,
    float* __restrict__ gsum, float* __restrict__ gsq) {
  __shared__ u16 xs[4 * 64 * 64] __attribute__((aligned(16)));    // 32 KB
  __shared__ u16 tc[64 * 128] __attribute__((aligned(16)));       // 16 KB
  __shared__ u16 Wst[2][128 * 64] __attribute__((aligned(16)));   // 32 KB

  const int t = threadIdx.x;
  const int wave = t >> 6, lane = t & 63;
  const int wr = wave >> 1, wc = wave & 1;
  const int quad = lane >> 4, ln15 = lane & 15;
  const int row0 = blockIdx.x * 64;
  const int K2 = CHUNKS * 128;   // W2 row stride

  // ---- stage x rows row0..+63, all 256 cols (tiled: 4 contiguous 8K runs) --
  if (COMBINE) {
    // coeffs al|bl|aa|ba -> tc (as float[1024]); tc is dead until chunk 0
    float* cf = (float*)tc;
#pragma unroll
    for (int k = 0; k < 4; k++) cf[k * 256 + t] = st[1536 + k * 256 + t];
    __syncthreads();
    const size_t tbase = ((size_t)(row0 >> 7) << 15) + ((row0 & 64) << 6);
#pragma unroll
    for (int i = 0; i < 8; i++) {
      const int gid = t + i * 256;        // 0..2047 16B-chunks
      const int kstep = gid >> 9;
      const int fid = gid & 511;
      const size_t addr = tbase + kstep * 8192 + fid * 8;
      const s16x8 rl = *(const s16x8*)(A + addr);
      const s16x8 ra = *(const s16x8*)(Ara + addr);
      const int seg = (fid & 7) ^ ((fid >> 3) & 7);
      const int col = kstep * 64 + seg * 8;
      const float4 al0 = *(const float4*)(cf + col);
      const float4 al1 = *(const float4*)(cf + col + 4);
      const float4 bl0 = *(const float4*)(cf + 256 + col);
      const float4 bl1 = *(const float4*)(cf + 256 + col + 4);
      const float4 aa0 = *(const float4*)(cf + 512 + col);
      const float4 aa1 = *(const float4*)(cf + 512 + col + 4);
      const float4 ba0 = *(const float4*)(cf + 768 + col);
      const float4 ba1 = *(const float4*)(cf + 768 + col + 4);
      const float al[8] = {al0.x, al0.y, al0.z, al0.w, al1.x, al1.y, al1.z, al1.w};
      const float bl[8] = {bl0.x, bl0.y, bl0.z, bl0.w, bl1.x, bl1.y, bl1.z, bl1.w};
      const float aa[8] = {aa0.x, aa0.y, aa0.z, aa0.w, aa1.x, aa1.y, aa1.z, aa1.w};
      const float ba[8] = {ba0.x, ba0.y, ba0.z, ba0.w, ba1.x, ba1.y, ba1.z, ba1.w};
      s16x8 o;
#pragma unroll
      for (int j = 0; j < 8; j++)
        o[j] = (short)f2b(al[j] * b2f((u16)rl[j]) + bl[j] +
                          aa[j] * b2f((u16)ra[j]) + ba[j]);
      *(s16x8*)(xs + gid * 8) = o;
    }
    __syncthreads();   // xs ready (also: tc coeffs dead, reusable)
  } else {
    const u16* abase = A + ((size_t)(row0 >> 7) << 15) + ((row0 & 64) << 6);
#pragma unroll
    for (int i = 0; i < 8; i++) {
      const int gid = t + i * 256;        // 0..2047 16B-loads
      const int kstep = gid >> 9;         // 512 loads per 8 KB panel
      const int fid = gid & 511;
      glds16(abase + kstep * 8192 + fid * 8, xs + gid * 8);
    }
  }

  f32x4 acc2[2][8];
#pragma unroll
  for (int i = 0; i < 2; i++)
#pragma unroll
    for (int j = 0; j < 8; j++) acc2[i][j] = (f32x4){0.f, 0.f, 0.f, 0.f};

  // t-chunk LDS addressing: 128 cols = 16 segs of 16B; XOR low 3 seg bits
  // with row so 16-lane column-slice b128 reads are conflict-free.
  auto tca = [&](int row, int col) {
    const int s0 = col >> 3;
    return row * 128 + (((s0 & 8) | ((s0 ^ row) & 7)) << 3) + (col & 7);
  };

  for (int c = 0; c < CHUNKS; c++) {
    // ================= GEMM1: tchunk = relu(x @ W1[c*128..+128]^T) =========
    f32x4 acc1[2][4];
#pragma unroll
    for (int i = 0; i < 2; i++)
#pragma unroll
      for (int j = 0; j < 4; j++) acc1[i][j] = (f32x4){0.f, 0.f, 0.f, 0.f};

    auto stage1 = [&](int b, int kt) {  // W1 rows c*128+(0..127), cols kt..+63
#pragma unroll
      for (int i = 0; i < 4; i++) {
        const int fid = t + i * 256;      // 0..1023
        const int row = fid >> 3;         // 0..127
        const int segp = (fid & 7) ^ (row & 7);
        glds16(W1 + (size_t)(c * 128 + row) * 256 + kt + segp * 8,
               &Wst[b][fid * 8]);
      }
    };

    stage1(0, 0);
    for (int kt = 0; kt < 256; kt += 64) {
      const int cur = (kt >> 6) & 1;
      if (kt + 64 < 256) {
        stage1(cur ^ 1, kt + 64);
        asm volatile("s_waitcnt vmcnt(4)" ::: "memory");
      } else {
        asm volatile("s_waitcnt vmcnt(0)" ::: "memory");
      }
      __builtin_amdgcn_s_barrier();
#pragma unroll
      for (int ks = 0; ks < 64; ks += 32) {
        s16x8 af[2], bf[4];
#pragma unroll
        for (int i = 0; i < 2; i++) {
          const int ra = wr * 32 + i * 16 + ln15;
          af[i] = *(const s16x8*)(
              &xs[(kt >> 6) * 4096 + ra * 64 +
                  ((((ks >> 3) + quad) ^ (ra & 7)) * 8)]);
        }
#pragma unroll
        for (int j = 0; j < 4; j++) {
          const int rb = wc * 64 + j * 16 + ln15;
          bf[j] = *(const s16x8*)(
              &Wst[cur][rb * 64 + ((((ks >> 3) + quad) ^ (rb & 7)) * 8)]);
        }
#pragma unroll
        for (int i = 0; i < 2; i++)
#pragma unroll
          for (int j = 0; j < 4; j++)
            acc1[i][j] = __builtin_amdgcn_mfma_f32_16x16x32_bf16(af[i], bf[j], acc1[i][j], 0, 0, 0);
      }
      __builtin_amdgcn_s_barrier();
    }

    // relu + bias -> tc (bf16)
    {
      float b1s[4];
#pragma unroll
      for (int j = 0; j < 4; j++)
        b1s[j] = b2f(b1[c * 128 + wc * 64 + j * 16 + ln15]);
#pragma unroll
      for (int i = 0; i < 2; i++)
#pragma unroll
        for (int reg = 0; reg < 4; reg++) {
          const int rowl = wr * 32 + i * 16 + quad * 4 + reg;
#pragma unroll
          for (int j = 0; j < 4; j++) {
            const int coll = wc * 64 + j * 16 + ln15;
            tc[tca(rowl, coll)] = f2b(fmaxf(acc1[i][j][reg] + b1s[j], 0.f));
          }
        }
    }
    __syncthreads();   // tc ready; Wst free

    // ================= GEMM2: acc2 += tchunk @ W2[:, c*128..+128]^T ========
    for (int ks2 = 0; ks2 < 2; ks2++) {   // two 64-wide K-steps
      // stage W2 rows 0..255, cols c*128 + ks2*64 -> Wst (32 KB, both bufs)
#pragma unroll
      for (int i = 0; i < 8; i++) {
        const int fid = t + i * 256;      // 0..2047
        const int row = fid >> 3;         // 0..255
        const int segp = (fid & 7) ^ (row & 7);
        glds16(W2 + (size_t)row * K2 + c * 128 + ks2 * 64 + segp * 8,
               &Wst[0][fid * 8]);
      }
      asm volatile("s_waitcnt vmcnt(0)" ::: "memory");
      __builtin_amdgcn_s_barrier();
#pragma unroll
      for (int ksl = 0; ksl < 64; ksl += 32) {
        s16x8 af[2], bf[8];
#pragma unroll
        for (int i = 0; i < 2; i++) {
          const int ra = wr * 32 + i * 16 + ln15;
          af[i] = *(const s16x8*)(&tc[tca(ra, ks2 * 64 + ksl + quad * 8)]);
        }
#pragma unroll
        for (int j = 0; j < 8; j++) {
          const int rb = wc * 128 + j * 16 + ln15;
          bf[j] = *(const s16x8*)(
              &Wst[0][rb * 64 + ((((ksl >> 3) + quad) ^ (rb & 7)) * 8)]);
        }
#pragma unroll
        for (int i = 0; i < 2; i++)
#pragma unroll
          for (int j = 0; j < 8; j++)
            acc2[i][j] = __builtin_amdgcn_mfma_f32_16x16x32_bf16(af[i], bf[j], acc2[i][j], 0, 0, 0);
      }
      __builtin_amdgcn_s_barrier();   // Wst/tc free for next stage/chunk
    }
  }

  // ---- epilogue: y = acc2 + b2 + res -> C (tiled) + stats ----
  float bs2[8];
#pragma unroll
  for (int j = 0; j < 8; j++)
    bs2[j] = b2f(b2[wc * 128 + j * 16 + ln15]);

  float ssum[8] = {}, ssq[8] = {};
#pragma unroll
  for (int i = 0; i < 2; i++) {
#pragma unroll
    for (int reg = 0; reg < 4; reg++) {
      const int rowl = wr * 32 + i * 16 + quad * 4 + reg;
      const int row = row0 + rowl;
#pragma unroll
      for (int j = 0; j < 8; j++) {
        const int col = wc * 128 + j * 16 + ln15;
        float val = acc2[i][j][reg] + bs2[j];
        if (RES_LDS) {
          val += b2f(xs[(col >> 6) * 4096 + rowl * 64 +
                        ((((col >> 3) & 7) ^ (rowl & 7)) << 3) + (col & 7)]);
        } else {
          val += b2f(resg[tix(row, col)]);
        }
        C[tix(row, col)] = f2b(val);
        ssum[j] += val; ssq[j] += val * val;
      }
    }
  }

#pragma unroll
  for (int j = 0; j < 8; j++) {
    float s = ssum[j];
    s += __shfl_xor(s, 16);
    s += __shfl_xor(s, 32);
    float q = ssq[j];
    q += __shfl_xor(q, 16);
    q += __shfl_xor(q, 32);
    if (lane < 16) {
      atomicAdd(&gsum[wc * 128 + j * 16 + lane], s);
      atomicAdd(&gsq[wc * 128 + j * 16 + lane], q);
    }
  }
}

// ---------------------------------------------------------------------------
// MFMA attention: one block per (graph, head), 4 waves; q/k/v/o tiled (tix).
// ---------------------------------------------------------------------------
__global__ __launch_bounds__(256) void attn_mfma(
    const u16* q, const u16* __restrict__ k,
    const u16* __restrict__ v, u16* o) {
  __shared__ u16 lds[21760] __attribute__((aligned(16)));
  u16* Vt = lds;                   // [32][136]  V transposed (d-major)
  u16* Qs = lds + 4352;            // [128][40]  scaled Q
  u16* Ks = lds + 4352 + 5120;     // [128][40]
  u16* P  = lds + 4352;            // [128][136] aliases Qs/Ks after barrier

  const int g = blockIdx.x >> 3;
  const int hd = blockIdx.x & 7;
  const int t = threadIdx.x;
  const int wave = t >> 6, lane = t & 63;
  const int quad = lane >> 4, ln15 = lane & 15;
  const int strip = wave * 32;
  const float scale = 0.1767766952966369f;  // 1/sqrt(32)

  // ---- stage Q (pre-scaled), K, V^T ----
#pragma unroll
  for (int i = 0; i < 4; i++) {
    const int fid = t + i * 256;   // 0..1023
    const int row = fid >> 3;
    const int seg = fid & 7;       // 4 u16 each
    const int gidx = tix(g * N_ + row, hd * HD_ + seg * 4);
    const ushort4 qv = *(const ushort4*)(q + gidx);
    const ushort4 kv = *(const ushort4*)(k + gidx);
    const ushort4 vv = *(const ushort4*)(v + gidx);
    ushort4 qs;
    qs.x = f2b(b2f(qv.x) * scale); qs.y = f2b(b2f(qv.y) * scale);
    qs.z = f2b(b2f(qv.z) * scale); qs.w = f2b(b2f(qv.w) * scale);
    *(ushort4*)(Qs + row * 40 + seg * 4) = qs;
    *(ushort4*)(Ks + row * 40 + seg * 4) = kv;
    Vt[(seg * 4 + 0) * 136 + row] = vv.x;
    Vt[(seg * 4 + 1) * 136 + row] = vv.y;
    Vt[(seg * 4 + 2) * 136 + row] = vv.z;
    Vt[(seg * 4 + 3) * 136 + row] = vv.w;
  }
  __syncthreads();

  // ---- S = Q K^T (strip x 128) ----
  s16x8 af[2], bf[8];
#pragma unroll
  for (int mi = 0; mi < 2; mi++)
    af[mi] = *(const s16x8*)(Qs + (strip + mi * 16 + ln15) * 40 + quad * 8);
#pragma unroll
  for (int nj = 0; nj < 8; nj++)
    bf[nj] = *(const s16x8*)(Ks + (nj * 16 + ln15) * 40 + quad * 8);

  f32x4 acc[2][8];
#pragma unroll
  for (int mi = 0; mi < 2; mi++)
#pragma unroll
    for (int nj = 0; nj < 8; nj++)
      acc[mi][nj] = __builtin_amdgcn_mfma_f32_16x16x32_bf16(
          af[mi], bf[nj], (f32x4){0.f, 0.f, 0.f, 0.f}, 0, 0, 0);

  __syncthreads();  // Q/K dead; region becomes P

  // ---- softmax per row, write P ----
#pragma unroll
  for (int mi = 0; mi < 2; mi++) {
#pragma unroll
    for (int reg = 0; reg < 4; reg++) {
      float mx = acc[mi][0][reg];
#pragma unroll
      for (int j = 1; j < 8; j++) mx = fmaxf(mx, acc[mi][j][reg]);
      mx = fmaxf(mx, __shfl_xor(mx, 1));
      mx = fmaxf(mx, __shfl_xor(mx, 2));
      mx = fmaxf(mx, __shfl_xor(mx, 4));
      mx = fmaxf(mx, __shfl_xor(mx, 8));
      float e[8], s = 0.f;
#pragma unroll
      for (int j = 0; j < 8; j++) { e[j] = __expf(acc[mi][j][reg] - mx); s += e[j]; }
      s += __shfl_xor(s, 1);
      s += __shfl_xor(s, 2);
      s += __shfl_xor(s, 4);
      s += __shfl_xor(s, 8);
      const float inv = 1.f / s;
      const int prow = strip + mi * 16 + quad * 4 + reg;
#pragma unroll
      for (int j = 0; j < 8; j++)
        P[prow * 136 + j * 16 + ln15] = f2b(e[j] * inv);
    }
  }
  __syncthreads();

  // ---- O = P V (strip x 32) ----
  f32x4 acc2[2][2];
#pragma unroll
  for (int mi = 0; mi < 2; mi++)
#pragma unroll
    for (int nj = 0; nj < 2; nj++) acc2[mi][nj] = (f32x4){0.f, 0.f, 0.f, 0.f};
#pragma unroll
  for (int kt = 0; kt < 4; kt++) {
    s16x8 paf[2], vbf[2];
#pragma unroll
    for (int mi = 0; mi < 2; mi++)
      paf[mi] = *(const s16x8*)(P + (strip + mi * 16 + ln15) * 136 + kt * 32 + quad * 8);
#pragma unroll
    for (int nj = 0; nj < 2; nj++)
      vbf[nj] = *(const s16x8*)(Vt + (nj * 16 + ln15) * 136 + kt * 32 + quad * 8);
#pragma unroll
    for (int mi = 0; mi < 2; mi++)
#pragma unroll
      for (int nj = 0; nj < 2; nj++)
        acc2[mi][nj] = __builtin_amdgcn_mfma_f32_16x16x32_bf16(
            paf[mi], vbf[nj], acc2[mi][nj], 0, 0, 0);
  }

#pragma unroll
  for (int mi = 0; mi < 2; mi++)
#pragma unroll
    for (int nj = 0; nj < 2; nj++)
#pragma unroll
      for (int reg = 0; reg < 4; reg++) {
        const int row = strip + mi * 16 + quad * 4 + reg;
        o[tix(g * N_ + row, hd * HD_ + nj * 16 + ln15)] =
            f2b(acc2[mi][nj][reg]);
      }
}

// BN finalize: a = g*rsqrt(var+eps); b' = b - mean*a   (fp32 params)
__global__ void bn_finalize(const float* __restrict__ sum,
                            const float* __restrict__ sq,
                            const float* __restrict__ g,
                            const float* __restrict__ bb,
                            float* __restrict__ a, float* __restrict__ b) {
  const int c = threadIdx.x;
  const float mean = sum[c] * (1.f / R_);
  const float var = fmaxf(sq[c] * (1.f / R_) - mean * mean, 0.f);
  const float ai = g[c] * rsqrtf(var + 1e-5f);
  a[c] = ai;
  b[c] = bb[c] - mean * ai;
}

// out = bn_out(y): tiled bf16 y -> linear fp32 out
__global__ __launch_bounds__(256) void final_kernel(
    const u16* __restrict__ y, const float* __restrict__ st,
    float* __restrict__ out) {
  const int e = (blockIdx.x * 256 + threadIdx.x) * 4;
  const int col = e & 255;
  float y4[4];
  ld4b(y + tix(e >> 8, col), y4);
  const float* ao = st + 2560;
  const float* bo = st + 2816;
  float4 o;
  o.x = ao[col + 0] * y4[0] + bo[col + 0];
  o.y = ao[col + 1] * y4[1] + bo[col + 1];
  o.z = ao[col + 2] * y4[2] + bo[col + 2];
  o.w = ao[col + 3] * y4[3] + bo[col + 3];
  *(float4*)(out + e) = o;
}

extern "C" void kernel_launch(void* const* d_in, const int* in_sizes, int n_in,
                              void* d_out, int out_size, void* d_ws, size_t ws_size,
                              hipStream_t stream) {
  const float* h = (const float*)d_in[0];
  const int* esrc = (const int*)d_in[1];
  const int* edst = (const int*)d_in[2];
  const float* bn_local_g = (const float*)d_in[11];
  const float* bn_local_b = (const float*)d_in[12];
  const float* bn_attn_g = (const float*)d_in[13];
  const float* bn_attn_b = (const float*)d_in[14];
  const float* bn_out_g = (const float*)d_in[15];
  const float* bn_out_b = (const float*)d_in[16];

  const size_t RH = (size_t)R_ * H_;
  float* stats = (float*)d_ws;                        // 3072 floats
  u16* WB = (u16*)((char*)d_ws + 65536);              // packed bf16 weights ~1.3 MB
  u16* Hb = (u16*)((char*)d_ws + 65536 + 2097152);    // h in bf16 (tiled), 32 MB
  u16* S1 = Hb + RH;                                  // 32 MB
  u16* S2 = S1 + RH;                                  // 32 MB
  u16* OD = (u16*)d_out;                              // first 32 MB of d_out as bf16 scratch
  float* outf = (float*)d_out;                        // final fp32 out (64 MB)

  zero_stats<<<12, 256, 0, stream>>>(stats);
  cvt_h<<<(int)(RH / 4 / 256), 256, 0, stream>>>(h, Hb);
  cvt_w<<<(W_TOTAL / 4 + 255) / 256, 256, 0, stream>>>(
      (const float*)d_in[3], (const float*)d_in[4], (const float*)d_in[5],
      (const float*)d_in[6], (const float*)d_in[7], (const float*)d_in[8],
      (const float*)d_in[9], (const float*)d_in[10], (const float*)d_in[17],
      (const float*)d_in[18], (const float*)d_in[19], (const float*)d_in[20], WB);

  // qkv: A staged once per block for all of q,k,v -> q=S1, k=S2, v=OD
  qkv_mfma<<<dim3(4, 1024), 256, 0, stream>>>(
      Hb, WB + OFF_AIW, WB + OFF_AIB, S1, S2, OD);
  // o = softmax(q k^T / sqrt(32)) v, in-place over q (S1)
  attn_mfma<<<B_ * NH_, 256, 0, stream>>>(S1, S2, OD, S1);
  // r_attn = h + o@Wo^T -> S2, + stats_attn
  gemm_mfma<256, 256, 0, 1, 1, 0, 0><<<dim3(4, 1024), 256, 0, stream>>>(
      S1, nullptr, WB + OFF_AOW, WB + OFF_AOB, Hb, S2, nullptr, nullptr,
      stats + 512, stats + 768);
  // z = h + segment_sum -> OD
  agg_kernel<<<dim3(B_, 4), 256, 0, stream>>>(Hb, esrc, edst, OD);
  // r_local = h + relu(z@GW1+b1)@GW2+b2 -> OD in place, + stats_local
  fused_mlp<2, 0, 0><<<1024, 256, 0, stream>>>(
      OD, nullptr, WB + OFF_GW1, WB + OFF_GB1, WB + OFF_GW2, WB + OFF_GB2,
      Hb, OD, nullptr, stats + 0, stats + 256);

  bn_finalize<<<1, 256, 0, stream>>>(stats + 0, stats + 256, bn_local_g,
                                     bn_local_b, stats + 1536, stats + 1792);
  bn_finalize<<<1, 256, 0, stream>>>(stats + 512, stats + 768, bn_attn_g,
                                     bn_attn_b, stats + 2048, stats + 2304);

  // y = x + relu(x@F1+b1)@F2+b2 -> S1, x = bn_l(OD)+bn_a(S2) computed in the
  // x-stage (combine kernel folded in), + stats_out
  fused_mlp<4, 1, 1><<<1024, 256, 0, stream>>>(
      OD, S2, WB + OFF_F1W, WB + OFF_F1B, WB + OFF_F2W, WB + OFF_F2B,
      nullptr, S1, stats, stats + 1024, stats + 1280);

  bn_finalize<<<1, 256, 0, stream>>>(stats + 1024, stats + 1280, bn_out_g,
                                     bn_out_b, stats + 2560, stats + 2816);
  // out = bn_out(y S1) -> fp32 d_out
  final_kernel<<<(int)(RH / 4 / 256), 256, 0, stream>>>(S1, stats, outf);
}